// Round 7
// baseline (465.717 us; speedup 1.0000x reference)
//
#include <hip/hip_runtime.h>
#include <hip/hip_bf16.h>
#include <math.h>

#define Bn 8
#define Cn 1152
#define Nn 1024   // H*W
#define NBPB 144  // blocks per batch (1152 total / 8 batches)

typedef short short8 __attribute__((ext_vector_type(8)));
typedef float f32x4 __attribute__((ext_vector_type(4)));

// Fully overwritten every call (each location written before read, ordered by barriers).
__device__ float g_csum_part[Bn * 128 * Nn];           // per-(b, i-stripe) partial col sums
__device__ unsigned short g_A[(size_t)Bn * Nn * Nn];   // E[b][i][j] = exp(w), unnormalized, bf16
__device__ unsigned short g_fb[(size_t)Bn * Cn * Nn];  // f_src[b][c][j] / csum[b][j], bf16

__device__ inline unsigned short f2bf(float x) {
    __hip_bfloat16 h = __float2bfloat16(x);
    unsigned short u;
    __builtin_memcpy(&u, &h, 2);
    return u;
}

__device__ inline void inv3(const float* M, float* o) {
    float a = M[0], b = M[1], c = M[2];
    float d = M[3], e = M[4], f = M[5];
    float g = M[6], h = M[7], i = M[8];
    float A0 = (e * i - f * h);
    float A1 = -(d * i - f * g);
    float A2 = (d * h - e * g);
    float det = a * A0 + b * A1 + c * A2;
    float inv = 1.0f / det;
    o[0] = A0 * inv;
    o[1] = -(b * i - c * h) * inv;
    o[2] = (b * f - c * e) * inv;
    o[3] = A1 * inv;
    o[4] = (a * i - c * g) * inv;
    o[5] = -(a * f - c * d) * inv;
    o[6] = A2 * inv;
    o[7] = -(a * h - b * g) * inv;
    o[8] = (a * e - b * d) * inv;
}

__device__ inline void mm3(const float* X, const float* Y, float* Z) {
    for (int r = 0; r < 3; r++)
        for (int c = 0; c < 3; c++)
            Z[r * 3 + c] = X[r * 3 + 0] * Y[0 * 3 + c] + X[r * 3 + 1] * Y[1 * 3 + c] +
                           X[r * 3 + 2] * Y[2 * 3 + c];
}

// F = inv(K2^T) skew(t) R inv(K1). SVD in the reference is a rank-2 no-op
// (skew(t)@R already has singular values (|t|,|t|,0)).
__device__ inline void computeF(const float* K1, const float* K2, const float* R,
                                const float* t, int b, float* F) {
    float t0 = t[b * 3 + 0], t1 = t[b * 3 + 1], t2 = t[b * 3 + 2];
    float S[9] = {0.0f, -t2, t1, t2, 0.0f, -t0, -t1, t0, 0.0f};
    float E[9];
    mm3(S, &R[b * 9], E);
    float iK1[9], iK2[9];
    inv3(&K1[b * 9], iK1);
    inv3(&K2[b * 9], iK2);
    float iK2T[9] = {iK2[0], iK2[3], iK2[6], iK2[1], iK2[4], iK2[7], iK2[2], iK2[5], iK2[8]};
    float T[9];
    mm3(iK2T, E, T);
    mm3(T, iK1, F);
}

// Per-j coefficients: z_ij = |ix*P + iy*Q - R| - 0.5  (== 5*(d_epi - 0.1))
__device__ inline float4 zcoef(const float* F, int j) {
    float jx = (float)(j >> 5);
    float jy = (float)(j & 31);
    float l0 = F[0] * jx + F[1] * jy + F[2];
    float l1 = F[3] * jx + F[4] * jy + F[5];
    float l2 = F[6] * jx + F[7] * jy + F[8];
    l0 = l0 / l2;
    l1 = l1 / l2;
    float y0 = -1.0f / l1;
    float y1 = -(1.0f + l0 * 32.0f) / l1;
    float dy = y0 - y1;
    float invn = 1.0f / sqrtf(1024.0f + dy * dy);
    return make_float4(5.0f * dy * invn, 160.0f * invn, 160.0f * y0 * invn, 0.0f);
}

// Device-scope barrier among the NBPB blocks of batch b. Counters zeroed by
// hipMemsetAsync each call. Release fence -> arrive -> spin -> acquire fence.
__device__ inline void batch_barrier(unsigned int* bar, int b, int ph) {
    __syncthreads();
    if (threadIdx.x == 0) {
        __threadfence();
        atomicAdd(&bar[ph * 8 + b], 1u);
        while (__hip_atomic_load(&bar[ph * 8 + b], __ATOMIC_RELAXED,
                                 __HIP_MEMORY_SCOPE_AGENT) < (unsigned)NBPB)
            __builtin_amdgcn_s_sleep(2);
        __threadfence();
    }
    __syncthreads();
}

#define BM 128
#define BNc 64
#define BK 32

// One fused launch: phase1 rowstats (own 8 rows) -> phase2 E + csum partials (own
// 8 rows, barrier-free since rmax is block-local) -> barrier A -> phase3 csum
// reduce + f_src scale/convert (own 8 channels) -> barrier B -> phase4 gemm
// (128i x 64c tile, 2 waves, dbuf LDS, global_load_lds, XOR k-quad swizzle).
// Grid 1152 x 128 thr: all co-resident (24 KB LDS -> 6 blocks/CU >= 4.5 needed).
__launch_bounds__(128) __global__
void fused_kernel(const float* __restrict__ f_src, const float* __restrict__ K1,
                  const float* __restrict__ K2, const float* __restrict__ Rm,
                  const float* __restrict__ tv, float* __restrict__ out,
                  unsigned int* __restrict__ bar) {
    __shared__ __align__(16) char smem[24576];
    // phases 1-2 view:
    float4* prm = (float4*)smem;                  // [1024] 16 KB
    float* rmv = (float*)(smem + 16384);          // [8]
    float* rsv = (float*)(smem + 16416);          // [8]
    float* Fsh = (float*)(smem + 16448);          // [9]
    // phase 4 view (disjoint in time):
    unsigned short* As0 = (unsigned short*)smem;            // [2][128*32] 16 KB
    unsigned short* Bs0 = (unsigned short*)(smem + 16384);  // [2][64*32]   8 KB

    int lin = blockIdx.x;
    int b = lin & 7;   // batch -> XCD (perf heuristic only)
    int s = lin >> 3;  // 0..143
    int t = threadIdx.x;

    if (t == 0) computeF(K1, K2, Rm, tv, b, Fsh);
    __syncthreads();

    if (s < 128) {
        // ---- phase 1: per-j coefficients (all 1024 j) + row stats for rows s*8..s*8+7
#pragma unroll
        for (int u = 0; u < 8; u++) {
            int j = t * 8 + u;
            prm[j] = zcoef(Fsh, j);
        }
        __syncthreads();
        int r0 = s * 8;
        int wv = t >> 6, lane = t & 63;
#pragma unroll
        for (int rr = 0; rr < 4; rr++) {
            int i = r0 + rr * 2 + wv;
            float ix = (float)(i >> 5), iy = (float)(i & 31);
            float z[16], m = -INFINITY;
#pragma unroll
            for (int k = 0; k < 16; k++) {
                float4 p = prm[lane + k * 64];
                z[k] = fabsf(fmaf(ix, p.x, fmaf(iy, p.y, -p.z))) - 0.5f;
                m = fmaxf(m, z[k]);
            }
#pragma unroll
            for (int o = 32; o > 0; o >>= 1) m = fmaxf(m, __shfl_xor(m, o, 64));
            float sm = 0.0f;
#pragma unroll
            for (int k = 0; k < 16; k++) sm += __expf(z[k] - m);
#pragma unroll
            for (int o = 32; o > 0; o >>= 1) sm += __shfl_xor(sm, o, 64);
            if (lane == 0) {
                rmv[rr * 2 + wv] = m;
                rsv[rr * 2 + wv] = 1.0f / sm;
            }
        }
        __syncthreads();
        // ---- phase 2: E rows (bf16) + this block's partial column sums
        int j0 = t * 8;
        float4 q[8];
#pragma unroll
        for (int u = 0; u < 8; u++) q[u] = prm[j0 + u];
        float cs[8] = {0.f, 0.f, 0.f, 0.f, 0.f, 0.f, 0.f, 0.f};
#pragma unroll
        for (int ii = 0; ii < 8; ii++) {
            int i = r0 + ii;
            float rmax = rmv[ii], rsi = rsv[ii];
            float ix = (float)(i >> 5), iy = (float)(i & 31);
            short8 ev;
#pragma unroll
            for (int u = 0; u < 8; u++) {
                float z = fabsf(fmaf(ix, q[u].x, fmaf(iy, q[u].y, -q[u].z))) - 0.5f;
                float E = __expf(1.0f - __expf(z - rmax) * rsi);
                cs[u] += E;
                ev[u] = (short)f2bf(E);
            }
            *(short8*)&g_A[((size_t)b * Nn + i) * Nn + j0] = ev;
        }
        float* cp = &g_csum_part[((size_t)b * 128 + s) * Nn + j0];
        *(float4*)cp = make_float4(cs[0], cs[1], cs[2], cs[3]);
        *(float4*)(cp + 4) = make_float4(cs[4], cs[5], cs[6], cs[7]);
    }
    batch_barrier(bar, b, 0);

    // ---- phase 3: reduce csum partials; scale+convert 8 channels of f_src to bf16
    {
        int j0 = t * 8;
        float4 a0 = make_float4(0.f, 0.f, 0.f, 0.f);
        float4 a1 = make_float4(0.f, 0.f, 0.f, 0.f);
#pragma unroll 4
        for (int p = 0; p < 128; p++) {
            const float* pp = &g_csum_part[((size_t)b * 128 + p) * Nn + j0];
            float4 v0 = *(const float4*)pp;
            float4 v1 = *(const float4*)(pp + 4);
            a0.x += v0.x; a0.y += v0.y; a0.z += v0.z; a0.w += v0.w;
            a1.x += v1.x; a1.y += v1.y; a1.z += v1.z; a1.w += v1.w;
        }
        float inv[8] = {1.0f / a0.x, 1.0f / a0.y, 1.0f / a0.z, 1.0f / a0.w,
                        1.0f / a1.x, 1.0f / a1.y, 1.0f / a1.z, 1.0f / a1.w};
#pragma unroll
        for (int cc = 0; cc < 8; cc++) {
            int c = s * 8 + cc;
            size_t off = ((size_t)b * Cn + c) * Nn + j0;
            float4 v0 = *(const float4*)(f_src + off);
            float4 v1 = *(const float4*)(f_src + off + 4);
            short8 u;
            u[0] = (short)f2bf(v0.x * inv[0]);
            u[1] = (short)f2bf(v0.y * inv[1]);
            u[2] = (short)f2bf(v0.z * inv[2]);
            u[3] = (short)f2bf(v0.w * inv[3]);
            u[4] = (short)f2bf(v1.x * inv[4]);
            u[5] = (short)f2bf(v1.y * inv[5]);
            u[6] = (short)f2bf(v1.z * inv[6]);
            u[7] = (short)f2bf(v1.w * inv[7]);
            *(short8*)&g_fb[off] = u;
        }
    }
    batch_barrier(bar, b, 1);

    // ---- phase 4: gemm  out[b,i,c] = sum_j E * fb  (R6-verified structure)
    {
        int it = s & 7, ct = s >> 3;  // 8 i-tiles x 18 c-tiles = 144
        int i0 = it * BM, c0 = ct * BNc;
        int w = t >> 6, L = t & 63;
        const unsigned short* Ab = g_A + (size_t)b * Nn * Nn + (size_t)i0 * Nn;
        const unsigned short* Fb = g_fb + (size_t)b * Cn * Nn + (size_t)c0 * Nn;
        auto stage = [&](int p, int kt) {
            // A: 512 x 16B chunks, 4/thread
#pragma unroll
            for (int h = 0; h < 4; h++) {
                int chunk = h * 128 + t;
                int rr = chunk >> 2;
                int gq = (chunk & 3) ^ ((rr >> 1) & 3);
                const unsigned short* ga = Ab + (size_t)rr * Nn + kt + gq * 8;
                __builtin_amdgcn_global_load_lds(
                    (const __attribute__((address_space(1))) unsigned int*)ga,
                    (__attribute__((address_space(3))) unsigned int*)(As0 + p * 4096 + chunk * 8),
                    16, 0, 0);
            }
            // B: 256 x 16B chunks, 2/thread
#pragma unroll
            for (int h = 0; h < 2; h++) {
                int chunk = h * 128 + t;
                int rr = chunk >> 2;
                int gq = (chunk & 3) ^ ((rr >> 1) & 3);
                const unsigned short* gb = Fb + (size_t)rr * Nn + kt + gq * 8;
                __builtin_amdgcn_global_load_lds(
                    (const __attribute__((address_space(1))) unsigned int*)gb,
                    (__attribute__((address_space(3))) unsigned int*)(Bs0 + p * 2048 + chunk * 8),
                    16, 0, 0);
            }
        };
        f32x4 acc[4][4] = {};
        int lrow = L & 15, quad = L >> 4;
        stage(0, 0);
        for (int kt = 0; kt < Nn; kt += BK) {
            int p = (kt >> 5) & 1;
            __syncthreads();  // vmcnt(0): buffer p staged; prev compute retired
            if (kt + BK < Nn) stage(1 - p, kt + BK);
            short8 af[4], bf[4];
#pragma unroll
            for (int mt = 0; mt < 4; mt++) {
                int rr = w * 64 + mt * 16 + lrow;
                int q = quad ^ ((rr >> 1) & 3);
                af[mt] = *(const short8*)(As0 + p * 4096 + rr * BK + q * 8);
            }
#pragma unroll
            for (int nt = 0; nt < 4; nt++) {
                int cc = nt * 16 + lrow;
                int q = quad ^ ((cc >> 1) & 3);
                bf[nt] = *(const short8*)(Bs0 + p * 2048 + cc * BK + q * 8);
            }
#pragma unroll
            for (int mt = 0; mt < 4; mt++)
#pragma unroll
                for (int nt = 0; nt < 4; nt++)
                    acc[mt][nt] = __builtin_amdgcn_mfma_f32_16x16x32_bf16(af[mt], bf[nt],
                                                                          acc[mt][nt], 0, 0, 0);
        }
        // Epilogue: D col=lane&15, row=(lane>>4)*4+reg  [m89-verified]
        int col = L & 15;
#pragma unroll
        for (int mt = 0; mt < 4; mt++)
#pragma unroll
            for (int rg = 0; rg < 4; rg++) {
                int i = i0 + w * 64 + mt * 16 + quad * 4 + rg;
                float* orow = out + ((size_t)b * Nn + i) * Cn + c0;
#pragma unroll
                for (int nt = 0; nt < 4; nt++) orow[nt * 16 + col] = acc[mt][nt][rg];
            }
    }
}

extern "C" void kernel_launch(void* const* d_in, const int* in_sizes, int n_in,
                              void* d_out, int out_size, void* d_ws, size_t ws_size,
                              hipStream_t stream) {
    (void)in_sizes; (void)n_in; (void)ws_size; (void)out_size;
    const float* f_src = (const float*)d_in[1];  // d_in[0] = f_tar unused by reference
    const float* K1 = (const float*)d_in[2];
    const float* K2 = (const float*)d_in[3];
    const float* R = (const float*)d_in[4];
    const float* t = (const float*)d_in[5];
    float* out = (float*)d_out;
    unsigned int* bar = (unsigned int*)d_ws;

    hipMemsetAsync(bar, 0, 64, stream);  // 2 phases x 8 batches of barrier counters
    fused_kernel<<<dim3(Bn * NBPB), dim3(128), 0, stream>>>(f_src, K1, K2, R, t, out, bar);
}

// Round 8
// 170.274 us; speedup vs baseline: 2.7351x; 2.7351x over previous
//
#include <hip/hip_runtime.h>
#include <hip/hip_bf16.h>
#include <math.h>

#define Bn 8
#define Cn 1152
#define Nn 1024  // H*W

typedef short short8 __attribute__((ext_vector_type(8)));
typedef float f32x4 __attribute__((ext_vector_type(4)));

// Softmax state. Fully overwritten every call.
__device__ float g_rmax[Bn * Nn];
__device__ float g_rsuminv[Bn * Nn];
__device__ float g_csum_part[Bn * 8 * Nn];  // per-(b, i-tile) partial column sums
// bf16 operands for the MFMA GEMM. Fully overwritten every call.
__device__ unsigned short g_A[(size_t)Bn * Nn * Nn];   // E[b][i][j] = exp(w) (unnormalized)
__device__ unsigned short g_fb[(size_t)Bn * Cn * Nn];  // f_src[b][c][j] / csum[b][j] in bf16

__device__ inline unsigned short f2bf(float x) {
    __hip_bfloat16 h = __float2bfloat16(x);
    unsigned short u;
    __builtin_memcpy(&u, &h, 2);
    return u;
}

__device__ inline void inv3(const float* M, float* o) {
    float a = M[0], b = M[1], c = M[2];
    float d = M[3], e = M[4], f = M[5];
    float g = M[6], h = M[7], i = M[8];
    float A0 = (e * i - f * h);
    float A1 = -(d * i - f * g);
    float A2 = (d * h - e * g);
    float det = a * A0 + b * A1 + c * A2;
    float inv = 1.0f / det;
    o[0] = A0 * inv;
    o[1] = -(b * i - c * h) * inv;
    o[2] = (b * f - c * e) * inv;
    o[3] = A1 * inv;
    o[4] = (a * i - c * g) * inv;
    o[5] = -(a * f - c * d) * inv;
    o[6] = A2 * inv;
    o[7] = -(a * h - b * g) * inv;
    o[8] = (a * e - b * d) * inv;
}

__device__ inline void mm3(const float* X, const float* Y, float* Z) {
    for (int r = 0; r < 3; r++)
        for (int c = 0; c < 3; c++)
            Z[r * 3 + c] = X[r * 3 + 0] * Y[0 * 3 + c] + X[r * 3 + 1] * Y[1 * 3 + c] +
                           X[r * 3 + 2] * Y[2 * 3 + c];
}

// F = inv(K2^T) skew(t) R inv(K1). SVD in the reference is a rank-2 no-op
// (skew(t)@R already has singular values (|t|,|t|,0)). Thread 0 per block.
__device__ inline void computeF(const float* K1, const float* K2, const float* R,
                                const float* t, int b, float* F) {
    float t0 = t[b * 3 + 0], t1 = t[b * 3 + 1], t2 = t[b * 3 + 2];
    float S[9] = {0.0f, -t2, t1, t2, 0.0f, -t0, -t1, t0, 0.0f};
    float E[9];
    mm3(S, &R[b * 9], E);
    float iK1[9], iK2[9];
    inv3(&K1[b * 9], iK1);
    inv3(&K2[b * 9], iK2);
    float iK2T[9] = {iK2[0], iK2[3], iK2[6], iK2[1], iK2[4], iK2[7], iK2[2], iK2[5], iK2[8]};
    float T[9];
    mm3(iK2T, E, T);
    mm3(T, iK1, F);
}

// Per-j coefficients: z_ij = |ix*P + iy*Q - R| - 0.5  (== 5*(d_epi - 0.1))
__device__ inline float4 zcoef(const float* F, int j) {
    float jx = (float)(j >> 5);
    float jy = (float)(j & 31);
    float l0 = F[0] * jx + F[1] * jy + F[2];
    float l1 = F[3] * jx + F[4] * jy + F[5];
    float l2 = F[6] * jx + F[7] * jy + F[8];
    l0 = l0 / l2;
    l1 = l1 / l2;
    float y0 = -1.0f / l1;
    float y1 = -(1.0f + l0 * 32.0f) / l1;
    float dy = y0 - y1;
    float invn = 1.0f / sqrtf(1024.0f + dy * dy);
    return make_float4(5.0f * dy * invn, 160.0f * invn, 160.0f * y0 * invn, 0.0f);
}

// Row softmax stats (over j). Grid 256: lin&7 = b = XCD, seg = lin>>3 owns rows
// seg*32..seg*32+31. zcoefs computed ONCE per block into LDS (8x less redundant
// precise-divide work than one-block-per-4-rows).
__global__ void rowstats_kernel(const float* __restrict__ K1, const float* __restrict__ K2,
                                const float* __restrict__ R, const float* __restrict__ t) {
    __shared__ float Fs[9];
    __shared__ float4 prm[Nn];
    int lin = blockIdx.x;
    int b = lin & 7;
    int seg = lin >> 3;  // 0..31
    if (threadIdx.x == 0) computeF(K1, K2, R, t, b, Fs);
    __syncthreads();
#pragma unroll
    for (int u = 0; u < 4; u++) {
        int j = threadIdx.x * 4 + u;
        prm[j] = zcoef(Fs, j);
    }
    __syncthreads();
    int wv = threadIdx.x >> 6;
    int lane = threadIdx.x & 63;
#pragma unroll
    for (int rr = 0; rr < 8; rr++) {
        int i = seg * 32 + wv * 8 + rr;
        float ix = (float)(i >> 5), iy = (float)(i & 31);
        float z[16], m = -INFINITY;
#pragma unroll
        for (int k = 0; k < 16; k++) {
            float4 p = prm[lane + k * 64];
            z[k] = fabsf(fmaf(ix, p.x, fmaf(iy, p.y, -p.z))) - 0.5f;
            m = fmaxf(m, z[k]);
        }
#pragma unroll
        for (int o = 32; o > 0; o >>= 1) m = fmaxf(m, __shfl_xor(m, o, 64));
        float s = 0.0f;
#pragma unroll
        for (int k = 0; k < 16; k++) s += __expf(z[k] - m);
#pragma unroll
        for (int o = 32; o > 0; o >>= 1) s += __shfl_xor(s, o, 64);
        if (lane == 0) {
            g_rmax[b * Nn + i] = m;
            g_rsuminv[b * Nn + i] = 1.0f / s;
        }
    }
}

// Fused column pass: E = exp(1 - rowsoftmax) as bf16 + per-(b,it) partial column
// sums. w in (0,1) so no max-subtraction needed. Grid 1024: lin&7 = b = XCD;
// jt = 16 tiles of 64 j, it = 8 tiles of 128 i. zcoefs once per block into LDS.
__global__ void colE_kernel(const float* __restrict__ K1, const float* __restrict__ K2,
                            const float* __restrict__ R, const float* __restrict__ t) {
    __shared__ float Fs[9];
    __shared__ float rm[128], rs[128];
    __shared__ float4 pj[64];
    __shared__ float4 red[16][16];
    int lin = blockIdx.x;
    int b = lin & 7;
    int r = lin >> 3;
    int jt = r & 15;
    int it = r >> 4;
    int tt = threadIdx.x;
    if (tt < 128) {
        rm[tt] = g_rmax[b * Nn + it * 128 + tt];
        rs[tt] = g_rsuminv[b * Nn + it * 128 + tt];
    }
    if (tt == 0) computeF(K1, K2, R, t, b, Fs);
    __syncthreads();
    if (tt < 64) pj[tt] = zcoef(Fs, jt * 64 + tt);
    __syncthreads();
    int tcol = tt & 15, trow = tt >> 4;
    int j0 = jt * 64 + tcol * 4;
    float4 p0 = pj[tcol * 4 + 0];
    float4 p1 = pj[tcol * 4 + 1];
    float4 p2 = pj[tcol * 4 + 2];
    float4 p3 = pj[tcol * 4 + 3];
    float4 csum = make_float4(0.f, 0.f, 0.f, 0.f);
#pragma unroll
    for (int k = 0; k < 8; k++) {
        int il = trow + k * 16;  // 0..127, each once
        float rmax = rm[il], rsi = rs[il];
        int i = it * 128 + il;
        float ix = (float)(i >> 5), iy = (float)(i & 31);
        float z0 = fabsf(fmaf(ix, p0.x, fmaf(iy, p0.y, -p0.z))) - 0.5f;
        float z1 = fabsf(fmaf(ix, p1.x, fmaf(iy, p1.y, -p1.z))) - 0.5f;
        float z2 = fabsf(fmaf(ix, p2.x, fmaf(iy, p2.y, -p2.z))) - 0.5f;
        float z3 = fabsf(fmaf(ix, p3.x, fmaf(iy, p3.y, -p3.z))) - 0.5f;
        float E0 = __expf(1.0f - __expf(z0 - rmax) * rsi);
        float E1 = __expf(1.0f - __expf(z1 - rmax) * rsi);
        float E2 = __expf(1.0f - __expf(z2 - rmax) * rsi);
        float E3 = __expf(1.0f - __expf(z3 - rmax) * rsi);
        csum.x += E0; csum.y += E1; csum.z += E2; csum.w += E3;
        ushort4 u;
        u.x = f2bf(E0); u.y = f2bf(E1); u.z = f2bf(E2); u.w = f2bf(E3);
        *(ushort4*)&g_A[((size_t)b * Nn + i) * Nn + j0] = u;
    }
    red[trow][tcol] = csum;
    __syncthreads();
    if (tt < 16) {
        float4 s = red[0][tt];
#pragma unroll
        for (int q = 1; q < 16; q++) {
            float4 p = red[q][tt];
            s.x += p.x; s.y += p.y; s.z += p.z; s.w += p.w;
        }
        *(float4*)&g_csum_part[(b * 8 + it) * Nn + jt * 64 + tt * 4] = s;
    }
}

// f_src fp32 -> bf16 scaled by 1/csum[b][j], 8 channels per block (csum loaded once).
// Grid 1152: lin&7 = b = XCD, cg = lin>>3 (0..143) = 8-channel group.
__global__ void convert_fsrc_kernel(const float* __restrict__ f) {
    int lin = blockIdx.x;
    int b = lin & 7;
    int cg = lin >> 3;
    int j0 = threadIdx.x * 4;
    float4 cs = *(const float4*)&g_csum_part[(b * 8 + 0) * Nn + j0];
#pragma unroll
    for (int it = 1; it < 8; it++) {
        float4 p = *(const float4*)&g_csum_part[(b * 8 + it) * Nn + j0];
        cs.x += p.x; cs.y += p.y; cs.z += p.z; cs.w += p.w;
    }
    float4 inv = make_float4(1.0f / cs.x, 1.0f / cs.y, 1.0f / cs.z, 1.0f / cs.w);
#pragma unroll
    for (int c8 = 0; c8 < 8; c8++) {
        int c = cg * 8 + c8;
        size_t off = ((size_t)b * Cn + c) * Nn + j0;
        float4 v = *(const float4*)(f + off);
        ushort4 u;
        u.x = f2bf(v.x * inv.x);
        u.y = f2bf(v.y * inv.y);
        u.z = f2bf(v.z * inv.z);
        u.w = f2bf(v.w * inv.w);
        *(ushort4*)&g_fb[off] = u;
    }
}

// out[b,i,c] = sum_j E[b,i,j] * fb_scaled[b,c,j]  — both operands K(j)-contiguous.
// 128(i) x 64(c) block-tile, 128 threads = 2 waves, each wave a 64x64 tile
// (4x4 mfma_16x16x32). Double-buffered LDS; 1152 blocks; lin&7 = b = XCD so
// per-batch A (2 MB) + fb (2.36 MB) stay in that XCD's 4 MB L2.
#define BM 128
#define BNc 64
#define BK 32

__launch_bounds__(128) __global__ void gemm_kernel(float* __restrict__ out) {
    __shared__ unsigned short As[2][BM * BK];   // 8 KB each
    __shared__ unsigned short Bs[2][BNc * BK];  // 4 KB each
    int lin = blockIdx.x;
    int b = lin & 7;
    int s = lin >> 3;  // 0..143
    int it = s & 7;
    int ct = s >> 3;   // 0..17
    int i0 = it * BM;
    int c0 = ct * BNc;
    int t = threadIdx.x;
    int w = t >> 6, L = t & 63;
    const unsigned short* Ab = g_A + (size_t)b * Nn * Nn + (size_t)i0 * Nn;
    const unsigned short* Fb = g_fb + (size_t)b * Cn * Nn + (size_t)c0 * Nn;

    auto stage = [&](int p, int kt) {
        // A: 512 x 16B chunks, 4/thread
#pragma unroll
        for (int h = 0; h < 4; h++) {
            int chunk = h * 128 + t;                 // 0..511
            int rr = chunk >> 2;                     // row 0..127
            int gq = (chunk & 3) ^ ((rr >> 1) & 3);  // swizzled global k-quad
            const unsigned short* ga = Ab + (size_t)rr * Nn + kt + gq * 8;
            __builtin_amdgcn_global_load_lds(
                (const __attribute__((address_space(1))) unsigned int*)ga,
                (__attribute__((address_space(3))) unsigned int*)(As[p] + chunk * 8), 16, 0, 0);
        }
        // B: 256 x 16B chunks, 2/thread
#pragma unroll
        for (int h = 0; h < 2; h++) {
            int chunk = h * 128 + t;                 // 0..255
            int rr = chunk >> 2;                     // row 0..63
            int gq = (chunk & 3) ^ ((rr >> 1) & 3);
            const unsigned short* gb = Fb + (size_t)rr * Nn + kt + gq * 8;
            __builtin_amdgcn_global_load_lds(
                (const __attribute__((address_space(1))) unsigned int*)gb,
                (__attribute__((address_space(3))) unsigned int*)(Bs[p] + chunk * 8), 16, 0, 0);
        }
    };

    f32x4 acc[4][4] = {};
    int lrow = L & 15, quad = L >> 4;
    stage(0, 0);
    for (int kt = 0; kt < Nn; kt += BK) {
        int p = (kt >> 5) & 1;
        __syncthreads();  // vmcnt(0): buffer p staged; prev compute retired
        if (kt + BK < Nn) stage(1 - p, kt + BK);  // in flight during compute below
        short8 af[4], bf[4];
#pragma unroll
        for (int mt = 0; mt < 4; mt++) {
            int rr = w * 64 + mt * 16 + lrow;
            int q = quad ^ ((rr >> 1) & 3);
            af[mt] = *(const short8*)(As[p] + rr * BK + q * 8);
        }
#pragma unroll
        for (int nt = 0; nt < 4; nt++) {
            int cc = nt * 16 + lrow;
            int q = quad ^ ((cc >> 1) & 3);
            bf[nt] = *(const short8*)(Bs[p] + cc * BK + q * 8);
        }
#pragma unroll
        for (int mt = 0; mt < 4; mt++)
#pragma unroll
            for (int nt = 0; nt < 4; nt++)
                acc[mt][nt] =
                    __builtin_amdgcn_mfma_f32_16x16x32_bf16(af[mt], bf[nt], acc[mt][nt], 0, 0, 0);
    }
    // Epilogue: D col=lane&15, row=(lane>>4)*4+reg  [m89-verified]
    int col = L & 15;
#pragma unroll
    for (int mt = 0; mt < 4; mt++)
#pragma unroll
        for (int rg = 0; rg < 4; rg++) {
            int i = i0 + w * 64 + mt * 16 + quad * 4 + rg;
            float* orow = out + ((size_t)b * Nn + i) * Cn + c0;
#pragma unroll
            for (int nt = 0; nt < 4; nt++) orow[nt * 16 + col] = acc[mt][nt][rg];
        }
}

extern "C" void kernel_launch(void* const* d_in, const int* in_sizes, int n_in,
                              void* d_out, int out_size, void* d_ws, size_t ws_size,
                              hipStream_t stream) {
    (void)in_sizes; (void)n_in; (void)d_ws; (void)ws_size; (void)out_size;
    const float* f_src = (const float*)d_in[1];  // d_in[0] = f_tar unused by reference
    const float* K1 = (const float*)d_in[2];
    const float* K2 = (const float*)d_in[3];
    const float* R = (const float*)d_in[4];
    const float* t = (const float*)d_in[5];
    float* out = (float*)d_out;

    rowstats_kernel<<<dim3(256), dim3(256), 0, stream>>>(K1, K2, R, t);
    colE_kernel<<<dim3(1024), dim3(256), 0, stream>>>(K1, K2, R, t);
    convert_fsrc_kernel<<<dim3(Bn * Cn / 8), dim3(256), 0, stream>>>(f_src);
    gemm_kernel<<<dim3(Bn * (Nn / BM) * (Cn / BNc)), dim3(128), 0, stream>>>(out);
}